// Round 10
// baseline (268.259 us; speedup 1.0000x reference)
//
#include <hip/hip_runtime.h>
#include <hip/hip_bf16.h>
#include <math.h>

#define N_NODES 50000
#define N_EDGES 800000
#define IN_DIM 256
#define HID 32
#define HEADS 4
#define OUT_DIM 64

#define SCAN_CHUNK 1024
#define SCAN_BLOCKS ((N_NODES + SCAN_CHUNK - 1) / SCAN_CHUNK)  // 49

typedef __attribute__((ext_vector_type(8))) short bf16x8;
typedef __attribute__((ext_vector_type(4))) float f32x4;

__device__ __forceinline__ float lrelu(float e) { return e > 0.f ? e : 0.01f * e; }
__device__ __forceinline__ float bflo(unsigned u) { return __uint_as_float(u << 16); }
__device__ __forceinline__ float bfhi(unsigned u) { return __uint_as_float(u & 0xffff0000u); }

// RNE float->bf16
__device__ __forceinline__ unsigned short rne_bf16(float x) {
    unsigned u = __float_as_uint(x);
    unsigned r = u + 0x7fffu + ((u >> 16) & 1u);
    return (unsigned short)(r >> 16);
}

// A-operand split (truncate hi + residual)
__device__ __forceinline__ void splitf(float x, short& hi, short& lo) {
    unsigned u = __float_as_uint(x);
    unsigned short h = (unsigned short)(u >> 16);
    float hf = __uint_as_float(((unsigned)h) << 16);
    float l = x - hf;
    unsigned short lb = (unsigned short)(__float_as_uint(l) >> 16);
    hi = (short)h;
    lo = (short)lb;
}

// ---------------- prep: zero count + both B-fragment packs ----------------

__global__ void __launch_bounds__(256) prep_kernel(
        const float* __restrict__ W1, const float* __restrict__ a1,
        const float* __restrict__ W2, const float* __restrict__ a2,
        unsigned short* __restrict__ B1h, unsigned short* __restrict__ B1l,
        unsigned short* __restrict__ B2h, unsigned short* __restrict__ B2l,
        int* __restrict__ count) {
    int gid = blockIdx.x * 256 + threadIdx.x;
    if (gid < N_NODES) count[gid] = 0;

    int k = blockIdx.x;       // 0..255
    int c = threadIdx.x;
    if (c < 144) {
        float val = 0.f;
        if (c < 128) {
            val = W1[(size_t)(c >> 5) * IN_DIM * HID + (size_t)k * HID + (c & 31)];
        } else if (c < 136) {
            int j = c - 128;
            int hd = (j < 4) ? j : (j - 4);
            int off = (j < 4) ? 0 : HID;
            const float* Wp = W1 + (size_t)hd * IN_DIM * HID + (size_t)k * HID;
            const float* ap = a1 + hd * 2 * HID + off;
            float s = 0.f;
            for (int o = 0; o < HID; o++) s += Wp[o] * ap[o];
            val = s;
        }
        unsigned short hi = rne_bf16(val);
        float hf = __uint_as_float(((unsigned)hi) << 16);
        unsigned short lo = rne_bf16(val - hf);
        int s_ = k >> 5, q = (k >> 3) & 3, j8 = k & 7;
        int nt = c >> 4, L = q * 16 + (c & 15);
        size_t idx = (((size_t)s_ * 9 + nt) * 64 + L) * 8 + j8;
        B1h[idx] = hi;
        B1l[idx] = lo;
    } else if (c >= 160 && c < 240 && k < 128) {
        int c2 = c - 160;
        float val = 0.f;
        if (c2 < 64) {
            val = W2[(size_t)k * OUT_DIM + c2];
        } else if (c2 < 66) {
            const float* ap = a2 + (c2 - 64) * OUT_DIM;
            const float* Wp = W2 + (size_t)k * OUT_DIM;
            float s = 0.f;
            for (int o = 0; o < OUT_DIM; o++) s += Wp[o] * ap[o];
            val = s;
        }
        unsigned short hi = rne_bf16(val);
        float hf = __uint_as_float(((unsigned)hi) << 16);
        unsigned short lo = rne_bf16(val - hf);
        int s_ = k >> 5, q = (k >> 3) & 3, j8 = k & 7;
        int nt = c2 >> 4, L = q * 16 + (c2 & 15);
        size_t idx = (((size_t)s_ * 5 + nt) * 64 + L) * 8 + j8;
        B2h[idx] = hi;
        B2l[idx] = lo;
    }
}

// ---------------- CSR build (by dst) ----------------

__global__ void hist_kernel(const int* __restrict__ dst, int* __restrict__ count,
                            int* __restrict__ rank) {
    int i = blockIdx.x * blockDim.x + threadIdx.x;
    if (i < N_EDGES) rank[i] = atomicAdd(&count[dst[i]], 1);
}

__global__ void scan1_kernel(const int* __restrict__ count, int* __restrict__ row_start,
                             int* __restrict__ blocksum) {
    __shared__ int sdata[256];
    int t = threadIdx.x;
    int base = blockIdx.x * SCAN_CHUNK + t * 4;
    int v[4];
    int s = 0;
#pragma unroll
    for (int j = 0; j < 4; j++) {
        int idx = base + j;
        int x = (idx < N_NODES) ? count[idx] : 0;
        v[j] = x;
        s += x;
    }
    sdata[t] = s;
    __syncthreads();
    for (int off = 1; off < 256; off <<= 1) {
        int u = (t >= off) ? sdata[t - off] : 0;
        __syncthreads();
        sdata[t] += u;
        __syncthreads();
    }
    int excl = sdata[t] - s;
#pragma unroll
    for (int j = 0; j < 4; j++) {
        int idx = base + j;
        if (idx < N_NODES) row_start[idx] = excl;
        excl += v[j];
    }
    if (t == 255) blocksum[blockIdx.x] = sdata[255];
}

__global__ void scan23_kernel(int* __restrict__ row_start, const int* __restrict__ blocksum) {
    __shared__ int pre;
    int t = threadIdx.x;
    if (t < 64) {
        int v = (t < SCAN_BLOCKS) ? blocksum[t] : 0;
#pragma unroll
        for (int off = 1; off < 64; off <<= 1) {
            int u = __shfl_up(v, off);
            if (t >= off) v += u;
        }
        if (t == blockIdx.x) pre = v - blocksum[t];
    }
    __syncthreads();
    int add = pre;
    int base = blockIdx.x * SCAN_CHUNK + t * 4;
#pragma unroll
    for (int j = 0; j < 4; j++) {
        int idx = base + j;
        if (idx < N_NODES) row_start[idx] += add;
    }
}

__global__ void scatter_kernel(const int* __restrict__ src, const int* __restrict__ dst,
                               const int* __restrict__ rank, const int* __restrict__ row_start,
                               int* __restrict__ esrc, int* __restrict__ edst) {
    int i = blockIdx.x * blockDim.x + threadIdx.x;
    if (i < N_EDGES) {
        int d = dst[i];
        int pos = row_start[d] + rank[i];
        esrc[pos] = src[i];
        edst[pos] = d;
    }
}

// ---------------- Layer 1 projection via MFMA ----------------

__global__ void __launch_bounds__(256) proj1_mfma(
        const float* __restrict__ h, const unsigned short* __restrict__ Bh,
        const unsigned short* __restrict__ Bl, __hip_bfloat16* __restrict__ z1b,
        float* __restrict__ es1, float* __restrict__ ed1) {
    int tid = threadIdx.x;
    int wave = tid >> 6;
    int L = tid & 63;
    int q = L >> 4, L15 = L & 15;
    int n0 = blockIdx.x * 64 + wave * 16;

    int rowA = n0 + L15;
    int rrA = rowA < N_NODES ? rowA : N_NODES - 1;
    const float* hrow = h + (size_t)rrA * IN_DIM + q * 8;

    f32x4 acc[9];
#pragma unroll
    for (int nt = 0; nt < 9; nt++) acc[nt] = (f32x4)(0.f);

    float4 x0 = *(const float4*)(hrow);
    float4 x1 = *(const float4*)(hrow + 4);

#pragma unroll
    for (int s = 0; s < 8; s++) {
        int sn = (s < 7) ? s + 1 : 7;
        float4 p0 = *(const float4*)(hrow + sn * 32);
        float4 p1 = *(const float4*)(hrow + sn * 32 + 4);

        float xs[8] = {x0.x, x0.y, x0.z, x0.w, x1.x, x1.y, x1.z, x1.w};
        bf16x8 ah, al;
#pragma unroll
        for (int j = 0; j < 8; j++) {
            short hi, lo;
            splitf(xs[j], hi, lo);
            ah[j] = hi;
            al[j] = lo;
        }

        const bf16x8* bhp = (const bf16x8*)(Bh + ((size_t)s * 9 * 64) * 8 + (size_t)L * 8);
        const bf16x8* blp = (const bf16x8*)(Bl + ((size_t)s * 9 * 64) * 8 + (size_t)L * 8);
#pragma unroll
        for (int nt = 0; nt < 9; nt++) {
            bf16x8 bh = bhp[nt * 64];
            acc[nt] = __builtin_amdgcn_mfma_f32_16x16x32_bf16(ah, bh, acc[nt], 0, 0, 0);
            acc[nt] = __builtin_amdgcn_mfma_f32_16x16x32_bf16(al, bh, acc[nt], 0, 0, 0);
        }
        {
            bf16x8 bl8 = blp[8 * 64];
            acc[8] = __builtin_amdgcn_mfma_f32_16x16x32_bf16(ah, bl8, acc[8], 0, 0, 0);
        }
        x0 = p0;
        x1 = p1;
    }

#pragma unroll
    for (int r = 0; r < 4; r++) {
        int rowc = n0 + q * 4 + r;
        if (rowc < N_NODES) {
#pragma unroll
            for (int nt = 0; nt < 8; nt++)
                z1b[(size_t)rowc * 128 + nt * 16 + L15] = __float2bfloat16(acc[nt][r]);
            if (L15 < 4) es1[rowc * HEADS + L15] = acc[8][r];
            else if (L15 < 8) ed1[rowc * HEADS + (L15 - 4)] = acc[8][r];
        }
    }
}

// ---------------- Edge p precompute (no atomics, streaming) ----------------
// p1[hd][pos] = exp(lrelu(es1[src][hd] + ed1[dst][hd])), CSR-ordered.
// Safe without max-subtraction: e in [-0.3, ~25] (leaky_relu compresses
// negatives 100x) so exp never over/underflows; denom >= 0.74*deg.

__global__ void edge1_p(const int* __restrict__ esrc, const int* __restrict__ edst,
                        const float* __restrict__ es1, const float* __restrict__ ed1,
                        float* __restrict__ p1) {
    int pos = blockIdx.x * 256 + threadIdx.x;
    if (pos >= N_EDGES) return;
    int s = esrc[pos], d = edst[pos];
    float4 es = *(const float4*)(es1 + 4 * (size_t)s);
    float4 ed = *(const float4*)(ed1 + 4 * (size_t)d);
    p1[0 * (size_t)N_EDGES + pos] = __expf(lrelu(es.x + ed.x));
    p1[1 * (size_t)N_EDGES + pos] = __expf(lrelu(es.y + ed.y));
    p1[2 * (size_t)N_EDGES + pos] = __expf(lrelu(es.z + ed.z));
    p1[3 * (size_t)N_EDGES + pos] = __expf(lrelu(es.w + ed.w));
}

__global__ void edge2_p(const int* __restrict__ esrc, const int* __restrict__ edst,
                        const float* __restrict__ es2, const float* __restrict__ ed2,
                        float* __restrict__ p2) {
    int pos = blockIdx.x * 256 + threadIdx.x;
    if (pos >= N_EDGES) return;
    p2[pos] = __expf(lrelu(es2[esrc[pos]] + ed2[edst[pos]]));
}

// ---------------- Layer 1 aggregation + ELU ----------------
// One wave per node; no shuffles / exps in the loop. Lane L = (sub=L>>4
// edge-in-group-of-4, c16=L&15 16B segment, hd=c16>>2). Per group of 4
// edges: direct loads se=esrc[beg+e] (1 line/wave), q=p1[hd*NE+beg+e]
// (4 lines), z=zq[se*16+c16] (4 rows/wave, depends on se only).
// 32 edges per outer iter, group-level wave-uniform guards.
// Denominator: per-lane sum of q (4x replicated), one epilogue reduction.

__global__ void __launch_bounds__(256) agg1_kernel(
        const __hip_bfloat16* __restrict__ z1b, const float* __restrict__ p1,
        const int* __restrict__ row_start, const int* __restrict__ count,
        const int* __restrict__ esrc, __hip_bfloat16* __restrict__ h1b) {
    int v = blockIdx.x * 4 + (threadIdx.x >> 6);
    int L = threadIdx.x & 63;
    int sub = L >> 4;
    int c16 = L & 15;
    int hd = c16 >> 2;
    int beg = row_start[v], deg = count[v];
    const float* ph = p1 + (size_t)hd * N_EDGES + beg;
    const int* ep = esrc + beg;
    float lacc = 0.f;
    float acc[8];
#pragma unroll
    for (int i = 0; i < 8; i++) acc[i] = 0.f;
    const uint4* zq = (const uint4*)z1b;   // row = 16 uint4

    for (int j0 = 0; j0 < deg; j0 += 32) {
        int se[8];
        float q[8];
        uint4 u[8];
#pragma unroll
        for (int g = 0; g < 8; g++) {
            if (j0 + g * 4 < deg) {               // wave-uniform
                int e = j0 + g * 4 + sub;
                bool val = e < deg;
                int idx = val ? e : 0;
                se[g] = ep[idx];
                float qq = ph[idx];
                q[g] = val ? qq : 0.f;
            }
        }
#pragma unroll
        for (int g = 0; g < 8; g++)
            if (j0 + g * 4 < deg) u[g] = zq[(size_t)se[g] * 16 + c16];
#pragma unroll
        for (int g = 0; g < 8; g++) {
            if (j0 + g * 4 < deg) {
                lacc += q[g];
                acc[0] = fmaf(q[g], bflo(u[g].x), acc[0]);
                acc[1] = fmaf(q[g], bfhi(u[g].x), acc[1]);
                acc[2] = fmaf(q[g], bflo(u[g].y), acc[2]);
                acc[3] = fmaf(q[g], bfhi(u[g].y), acc[3]);
                acc[4] = fmaf(q[g], bflo(u[g].z), acc[4]);
                acc[5] = fmaf(q[g], bfhi(u[g].z), acc[5]);
                acc[6] = fmaf(q[g], bflo(u[g].w), acc[6]);
                acc[7] = fmaf(q[g], bfhi(u[g].w), acc[7]);
            }
        }
    }
    // l per head: lanes of head hd differ in bits 0,1 (c16&3) and 4,5 (sub);
    // sum over them = 4 * l_hd.
    lacc += __shfl_xor(lacc, 1);
    lacc += __shfl_xor(lacc, 2);
    lacc += __shfl_xor(lacc, 16);
    lacc += __shfl_xor(lacc, 32);
    lacc *= 0.25f;
    // combine 4 edge-subgroups (bits 4,5)
#pragma unroll
    for (int i = 0; i < 8; i++) {
        acc[i] += __shfl_xor(acc[i], 16);
        acc[i] += __shfl_xor(acc[i], 32);
    }
    if (L < 16) {
        float inv = (deg > 0) ? 1.f / lacc : 0.f;
        unsigned w[4];
#pragma unroll
        for (int i = 0; i < 4; i++) {
            float r0 = acc[2 * i] * inv;
            float r1 = acc[2 * i + 1] * inv;
            r0 = r0 > 0.f ? r0 : __expf(r0) - 1.f;   // elu
            r1 = r1 > 0.f ? r1 : __expf(r1) - 1.f;
            w[i] = (unsigned)rne_bf16(r0) | ((unsigned)rne_bf16(r1) << 16);
        }
        uint4* dst = (uint4*)(h1b + (size_t)v * 128 + c16 * 8);
        *dst = make_uint4(w[0], w[1], w[2], w[3]);
    }
}

// ---------------- Layer 2 projection via MFMA (bf16 A, no split) ----------------

__global__ void __launch_bounds__(256) proj2_mfma(
        const __hip_bfloat16* __restrict__ h1b, const unsigned short* __restrict__ Bh,
        const unsigned short* __restrict__ Bl, __hip_bfloat16* __restrict__ z2b,
        float* __restrict__ es2, float* __restrict__ ed2) {
    int tid = threadIdx.x;
    int wave = tid >> 6;
    int L = tid & 63;
    int q = L >> 4, L15 = L & 15;
    int n0 = blockIdx.x * 64 + wave * 16;

    int rowA = n0 + L15;
    int rrA = rowA < N_NODES ? rowA : N_NODES - 1;
    const bf16x8* hq = (const bf16x8*)(h1b + (size_t)rrA * 128);

    f32x4 acc[5];
#pragma unroll
    for (int nt = 0; nt < 5; nt++) acc[nt] = (f32x4)(0.f);

#pragma unroll
    for (int s = 0; s < 4; s++) {
        bf16x8 a = hq[s * 4 + q];   // channels s*32 + q*8 .. +7
        const bf16x8* bhp = (const bf16x8*)(Bh + ((size_t)s * 5 * 64) * 8 + (size_t)L * 8);
        const bf16x8* blp = (const bf16x8*)(Bl + ((size_t)s * 5 * 64) * 8 + (size_t)L * 8);
#pragma unroll
        for (int nt = 0; nt < 5; nt++)
            acc[nt] = __builtin_amdgcn_mfma_f32_16x16x32_bf16(a, bhp[nt * 64], acc[nt], 0, 0, 0);
        acc[4] = __builtin_amdgcn_mfma_f32_16x16x32_bf16(a, blp[4 * 64], acc[4], 0, 0, 0);
    }

#pragma unroll
    for (int r = 0; r < 4; r++) {
        int rowc = n0 + q * 4 + r;
        if (rowc < N_NODES) {
#pragma unroll
            for (int nt = 0; nt < 4; nt++)
                z2b[(size_t)rowc * OUT_DIM + nt * 16 + L15] = __float2bfloat16(acc[nt][r]);
            if (L15 == 0) es2[rowc] = acc[4][r];
            else if (L15 == 1) ed2[rowc] = acc[4][r];
        }
    }
}

// ---------------- Layer 2 aggregation (final output) ----------------
// One wave per node; lane L = (sub=L>>3, c8=L&7); 32 edges per outer iter
// (4 groups of 8); q independent of c8 so l needs no scaling.

__global__ void __launch_bounds__(256) agg2_kernel(
        const __hip_bfloat16* __restrict__ z2b, const float* __restrict__ p2,
        const int* __restrict__ row_start, const int* __restrict__ count,
        const int* __restrict__ esrc, float* __restrict__ out) {
    int v = blockIdx.x * 4 + (threadIdx.x >> 6);
    int L = threadIdx.x & 63;
    int sub = L >> 3;
    int c8 = L & 7;
    int beg = row_start[v], deg = count[v];
    const float* ph = p2 + beg;
    const int* ep = esrc + beg;
    float lacc = 0.f;
    float acc[8];
#pragma unroll
    for (int i = 0; i < 8; i++) acc[i] = 0.f;
    const uint4* zq = (const uint4*)z2b;   // row = 8 uint4

    for (int j0 = 0; j0 < deg; j0 += 32) {
        int se[4];
        float q[4];
        uint4 u[4];
#pragma unroll
        for (int g = 0; g < 4; g++) {
            if (j0 + g * 8 < deg) {               // wave-uniform
                int e = j0 + g * 8 + sub;
                bool val = e < deg;
                int idx = val ? e : 0;
                se[g] = ep[idx];
                float qq = ph[idx];
                q[g] = val ? qq : 0.f;
            }
        }
#pragma unroll
        for (int g = 0; g < 4; g++)
            if (j0 + g * 8 < deg) u[g] = zq[(size_t)se[g] * 8 + c8];
#pragma unroll
        for (int g = 0; g < 4; g++) {
            if (j0 + g * 8 < deg) {
                lacc += q[g];
                acc[0] = fmaf(q[g], bflo(u[g].x), acc[0]);
                acc[1] = fmaf(q[g], bfhi(u[g].x), acc[1]);
                acc[2] = fmaf(q[g], bflo(u[g].y), acc[2]);
                acc[3] = fmaf(q[g], bfhi(u[g].y), acc[3]);
                acc[4] = fmaf(q[g], bflo(u[g].z), acc[4]);
                acc[5] = fmaf(q[g], bfhi(u[g].z), acc[5]);
                acc[6] = fmaf(q[g], bflo(u[g].w), acc[6]);
                acc[7] = fmaf(q[g], bfhi(u[g].w), acc[7]);
            }
        }
    }
    // l: lanes with same sub are identical; sum over subs (bits 3,4,5)
    lacc += __shfl_xor(lacc, 8);
    lacc += __shfl_xor(lacc, 16);
    lacc += __shfl_xor(lacc, 32);
    // combine 8 edge-subgroups
#pragma unroll
    for (int i = 0; i < 8; i++) {
        acc[i] += __shfl_xor(acc[i], 8);
        acc[i] += __shfl_xor(acc[i], 16);
        acc[i] += __shfl_xor(acc[i], 32);
    }
    if (L < 8) {
        float inv = (deg > 0) ? 1.f / lacc : 0.f;
        float4 r0, r1;
#pragma unroll
        for (int i = 0; i < 8; i++) {
            float r = acc[i] * inv;
            if (i < 4) (&r0.x)[i] = r;
            else (&r1.x)[i - 4] = r;
        }
        float* dst = out + (size_t)v * OUT_DIM + c8 * 8;
        *(float4*)dst = r0;
        *(float4*)(dst + 4) = r1;
    }
}

// ---------------- launch ----------------

extern "C" void kernel_launch(void* const* d_in, const int* in_sizes, int n_in,
                              void* d_out, int out_size, void* d_ws, size_t ws_size,
                              hipStream_t stream) {
    const float* h  = (const float*)d_in[0];
    const int* src  = (const int*)d_in[1];
    const int* dst  = (const int*)d_in[2];
    const float* W1 = (const float*)d_in[3];
    const float* a1 = (const float*)d_in[4];
    const float* W2 = (const float*)d_in[5];
    const float* a2 = (const float*)d_in[6];
    float* out = (float*)d_out;

    char* w = (char*)d_ws;
    size_t off = 0;
    auto alloc = [&](size_t bytes) {
        void* p = w + off;
        off = (off + bytes + 255) & ~(size_t)255;
        return p;
    };
    __hip_bfloat16* z1b = (__hip_bfloat16*)alloc((size_t)N_NODES * 128 * 2);
    float* es1 = (float*)alloc((size_t)N_NODES * HEADS * 4);
    float* ed1 = (float*)alloc((size_t)N_NODES * HEADS * 4);
    __hip_bfloat16* h1b = (__hip_bfloat16*)alloc((size_t)N_NODES * 128 * 2);
    __hip_bfloat16* z2b = (__hip_bfloat16*)alloc((size_t)N_NODES * OUT_DIM * 2);
    float* es2 = (float*)alloc((size_t)N_NODES * 4);
    float* ed2 = (float*)alloc((size_t)N_NODES * 4);
    int* count     = (int*)alloc((size_t)N_NODES * 4);
    int* row_start = (int*)alloc((size_t)N_NODES * 4);
    int* rank      = (int*)alloc((size_t)N_EDGES * 4);
    int* blocksum  = (int*)alloc((size_t)SCAN_BLOCKS * 4);
    int* esrc      = (int*)alloc((size_t)N_EDGES * 4);
    int* edst      = (int*)alloc((size_t)N_EDGES * 4);
    float* p1      = (float*)alloc((size_t)N_EDGES * HEADS * 4);
    float* p2      = (float*)alloc((size_t)N_EDGES * 4);
    unsigned short* Bf1h = (unsigned short*)alloc((size_t)8 * 9 * 64 * 8 * 2);
    unsigned short* Bf1l = (unsigned short*)alloc((size_t)8 * 9 * 64 * 8 * 2);
    unsigned short* Bf2h = (unsigned short*)alloc((size_t)4 * 5 * 64 * 8 * 2);
    unsigned short* Bf2l = (unsigned short*)alloc((size_t)4 * 5 * 64 * 8 * 2);

    prep_kernel<<<256, 256, 0, stream>>>(W1, a1, W2, a2, Bf1h, Bf1l, Bf2h, Bf2l, count);
    hist_kernel<<<(N_EDGES + 255) / 256, 256, 0, stream>>>(dst, count, rank);
    scan1_kernel<<<SCAN_BLOCKS, 256, 0, stream>>>(count, row_start, blocksum);
    scan23_kernel<<<SCAN_BLOCKS, 256, 0, stream>>>(row_start, blocksum);
    scatter_kernel<<<(N_EDGES + 255) / 256, 256, 0, stream>>>(src, dst, rank, row_start, esrc, edst);

    const int MBLK = (N_NODES + 63) / 64;  // 782
    proj1_mfma<<<MBLK, 256, 0, stream>>>(h, Bf1h, Bf1l, z1b, es1, ed1);
    edge1_p<<<(N_EDGES + 255) / 256, 256, 0, stream>>>(esrc, edst, es1, ed1, p1);
    agg1_kernel<<<N_NODES / 4, 256, 0, stream>>>(z1b, p1, row_start, count, esrc, h1b);
    proj2_mfma<<<MBLK, 256, 0, stream>>>(h1b, Bf2h, Bf2l, z2b, es2, ed2);
    edge2_p<<<(N_EDGES + 255) / 256, 256, 0, stream>>>(esrc, edst, es2, ed2, p2);
    agg2_kernel<<<N_NODES / 4, 256, 0, stream>>>(z2b, p2, row_start, count, esrc, out);
}

// Round 11
// 230.005 us; speedup vs baseline: 1.1663x; 1.1663x over previous
//
#include <hip/hip_runtime.h>
#include <hip/hip_bf16.h>
#include <math.h>

#define N_NODES 50000
#define N_EDGES 800000
#define IN_DIM 256
#define HID 32
#define HEADS 4
#define OUT_DIM 64

#define SCAN_CHUNK 1024
#define SCAN_BLOCKS ((N_NODES + SCAN_CHUNK - 1) / SCAN_CHUNK)  // 49

typedef __attribute__((ext_vector_type(8))) short bf16x8;
typedef __attribute__((ext_vector_type(4))) float f32x4;

__device__ __forceinline__ float lrelu(float e) { return e > 0.f ? e : 0.01f * e; }
__device__ __forceinline__ float bflo(unsigned u) { return __uint_as_float(u << 16); }
__device__ __forceinline__ float bfhi(unsigned u) { return __uint_as_float(u & 0xffff0000u); }

// RNE float->bf16
__device__ __forceinline__ unsigned short rne_bf16(float x) {
    unsigned u = __float_as_uint(x);
    unsigned r = u + 0x7fffu + ((u >> 16) & 1u);
    return (unsigned short)(r >> 16);
}

// A-operand split (truncate hi + residual)
__device__ __forceinline__ void splitf(float x, short& hi, short& lo) {
    unsigned u = __float_as_uint(x);
    unsigned short h = (unsigned short)(u >> 16);
    float hf = __uint_as_float(((unsigned)h) << 16);
    float l = x - hf;
    unsigned short lb = (unsigned short)(__float_as_uint(l) >> 16);
    hi = (short)h;
    lo = (short)lb;
}

// ---------------- prep: zero count + both B-fragment packs ----------------

__global__ void __launch_bounds__(256) prep_kernel(
        const float* __restrict__ W1, const float* __restrict__ a1,
        const float* __restrict__ W2, const float* __restrict__ a2,
        unsigned short* __restrict__ B1h, unsigned short* __restrict__ B1l,
        unsigned short* __restrict__ B2h, unsigned short* __restrict__ B2l,
        int* __restrict__ count) {
    int gid = blockIdx.x * 256 + threadIdx.x;
    if (gid < N_NODES) count[gid] = 0;

    int k = blockIdx.x;       // 0..255
    int c = threadIdx.x;
    if (c < 144) {
        float val = 0.f;
        if (c < 128) {
            val = W1[(size_t)(c >> 5) * IN_DIM * HID + (size_t)k * HID + (c & 31)];
        } else if (c < 136) {
            int j = c - 128;
            int hd = (j < 4) ? j : (j - 4);
            int off = (j < 4) ? 0 : HID;
            const float* Wp = W1 + (size_t)hd * IN_DIM * HID + (size_t)k * HID;
            const float* ap = a1 + hd * 2 * HID + off;
            float s = 0.f;
            for (int o = 0; o < HID; o++) s += Wp[o] * ap[o];
            val = s;
        }
        unsigned short hi = rne_bf16(val);
        float hf = __uint_as_float(((unsigned)hi) << 16);
        unsigned short lo = rne_bf16(val - hf);
        int s_ = k >> 5, q = (k >> 3) & 3, j8 = k & 7;
        int nt = c >> 4, L = q * 16 + (c & 15);
        size_t idx = (((size_t)s_ * 9 + nt) * 64 + L) * 8 + j8;
        B1h[idx] = hi;
        B1l[idx] = lo;
    } else if (c >= 160 && c < 240 && k < 128) {
        int c2 = c - 160;
        float val = 0.f;
        if (c2 < 64) {
            val = W2[(size_t)k * OUT_DIM + c2];
        } else if (c2 < 66) {
            const float* ap = a2 + (c2 - 64) * OUT_DIM;
            const float* Wp = W2 + (size_t)k * OUT_DIM;
            float s = 0.f;
            for (int o = 0; o < OUT_DIM; o++) s += Wp[o] * ap[o];
            val = s;
        }
        unsigned short hi = rne_bf16(val);
        float hf = __uint_as_float(((unsigned)hi) << 16);
        unsigned short lo = rne_bf16(val - hf);
        int s_ = k >> 5, q = (k >> 3) & 3, j8 = k & 7;
        int nt = c2 >> 4, L = q * 16 + (c2 & 15);
        size_t idx = (((size_t)s_ * 5 + nt) * 64 + L) * 8 + j8;
        B2h[idx] = hi;
        B2l[idx] = lo;
    }
}

// ---------------- CSR build (by dst) ----------------

__global__ void hist_kernel(const int* __restrict__ dst, int* __restrict__ count,
                            int* __restrict__ rank) {
    int i = blockIdx.x * blockDim.x + threadIdx.x;
    if (i < N_EDGES) rank[i] = atomicAdd(&count[dst[i]], 1);
}

__global__ void scan1_kernel(const int* __restrict__ count, int* __restrict__ row_start,
                             int* __restrict__ blocksum) {
    __shared__ int sdata[256];
    int t = threadIdx.x;
    int base = blockIdx.x * SCAN_CHUNK + t * 4;
    int v[4];
    int s = 0;
#pragma unroll
    for (int j = 0; j < 4; j++) {
        int idx = base + j;
        int x = (idx < N_NODES) ? count[idx] : 0;
        v[j] = x;
        s += x;
    }
    sdata[t] = s;
    __syncthreads();
    for (int off = 1; off < 256; off <<= 1) {
        int u = (t >= off) ? sdata[t - off] : 0;
        __syncthreads();
        sdata[t] += u;
        __syncthreads();
    }
    int excl = sdata[t] - s;
#pragma unroll
    for (int j = 0; j < 4; j++) {
        int idx = base + j;
        if (idx < N_NODES) row_start[idx] = excl;
        excl += v[j];
    }
    if (t == 255) blocksum[blockIdx.x] = sdata[255];
}

__global__ void scan23_kernel(int* __restrict__ row_start, const int* __restrict__ blocksum) {
    __shared__ int pre;
    int t = threadIdx.x;
    if (t < 64) {
        int v = (t < SCAN_BLOCKS) ? blocksum[t] : 0;
#pragma unroll
        for (int off = 1; off < 64; off <<= 1) {
            int u = __shfl_up(v, off);
            if (t >= off) v += u;
        }
        if (t == blockIdx.x) pre = v - blocksum[t];
    }
    __syncthreads();
    int add = pre;
    int base = blockIdx.x * SCAN_CHUNK + t * 4;
#pragma unroll
    for (int j = 0; j < 4; j++) {
        int idx = base + j;
        if (idx < N_NODES) row_start[idx] += add;
    }
}

__global__ void scatter_kernel(const int* __restrict__ src, const int* __restrict__ dst,
                               const int* __restrict__ rank, const int* __restrict__ row_start,
                               int* __restrict__ esrc) {
    int i = blockIdx.x * blockDim.x + threadIdx.x;
    if (i < N_EDGES) esrc[row_start[dst[i]] + rank[i]] = src[i];
}

// ---------------- Layer 1 projection via MFMA ----------------
// z-tiles: 2-term (Ahi+Alo)·Bh; logit tile: 3-term (es/ed fp32-accurate).

__global__ void __launch_bounds__(256) proj1_mfma(
        const float* __restrict__ h, const unsigned short* __restrict__ Bh,
        const unsigned short* __restrict__ Bl, __hip_bfloat16* __restrict__ z1b,
        float* __restrict__ es1, float* __restrict__ ed1) {
    int tid = threadIdx.x;
    int wave = tid >> 6;
    int L = tid & 63;
    int q = L >> 4, L15 = L & 15;
    int n0 = blockIdx.x * 64 + wave * 16;

    int rowA = n0 + L15;
    int rrA = rowA < N_NODES ? rowA : N_NODES - 1;
    const float* hrow = h + (size_t)rrA * IN_DIM + q * 8;

    f32x4 acc[9];
#pragma unroll
    for (int nt = 0; nt < 9; nt++) acc[nt] = (f32x4)(0.f);

    float4 x0 = *(const float4*)(hrow);
    float4 x1 = *(const float4*)(hrow + 4);

#pragma unroll
    for (int s = 0; s < 8; s++) {
        int sn = (s < 7) ? s + 1 : 7;
        float4 p0 = *(const float4*)(hrow + sn * 32);
        float4 p1 = *(const float4*)(hrow + sn * 32 + 4);

        float xs[8] = {x0.x, x0.y, x0.z, x0.w, x1.x, x1.y, x1.z, x1.w};
        bf16x8 ah, al;
#pragma unroll
        for (int j = 0; j < 8; j++) {
            short hi, lo;
            splitf(xs[j], hi, lo);
            ah[j] = hi;
            al[j] = lo;
        }

        const bf16x8* bhp = (const bf16x8*)(Bh + ((size_t)s * 9 * 64) * 8 + (size_t)L * 8);
        const bf16x8* blp = (const bf16x8*)(Bl + ((size_t)s * 9 * 64) * 8 + (size_t)L * 8);
#pragma unroll
        for (int nt = 0; nt < 9; nt++) {
            bf16x8 bh = bhp[nt * 64];
            acc[nt] = __builtin_amdgcn_mfma_f32_16x16x32_bf16(ah, bh, acc[nt], 0, 0, 0);
            acc[nt] = __builtin_amdgcn_mfma_f32_16x16x32_bf16(al, bh, acc[nt], 0, 0, 0);
        }
        {
            bf16x8 bl8 = blp[8 * 64];
            acc[8] = __builtin_amdgcn_mfma_f32_16x16x32_bf16(ah, bl8, acc[8], 0, 0, 0);
        }
        x0 = p0;
        x1 = p1;
    }

#pragma unroll
    for (int r = 0; r < 4; r++) {
        int rowc = n0 + q * 4 + r;
        if (rowc < N_NODES) {
#pragma unroll
            for (int nt = 0; nt < 8; nt++)
                z1b[(size_t)rowc * 128 + nt * 16 + L15] = __float2bfloat16(acc[nt][r]);
            if (L15 < 4) es1[rowc * HEADS + L15] = acc[8][r];
            else if (L15 < 8) ed1[rowc * HEADS + (L15 - 4)] = acc[8][r];
        }
    }
}

// ---------------- Layer 1 aggregation + ELU ----------------
// One wave per node; no shuffles. Lane L = (sub=L>>4, c16=L&15, hd=c16>>2).
// Inline p: after se[g] is known, the z-row gather (zq) and the tiny
// es1[se*4+hd] gather (L2-resident 800 KB table) issue in the same latency
// window; q = exp(lrelu(es+ed)) computed per-lane (redundant x4, pure VALU).
// No max subtraction: e in [-0.3, ~25] -> exp safe, denom >= 0.74*deg.

__global__ void __launch_bounds__(256) agg1_kernel(
        const __hip_bfloat16* __restrict__ z1b, const float* __restrict__ es1,
        const float* __restrict__ ed1, const int* __restrict__ row_start,
        const int* __restrict__ count, const int* __restrict__ esrc,
        __hip_bfloat16* __restrict__ h1b) {
    int v = blockIdx.x * 4 + (threadIdx.x >> 6);
    int L = threadIdx.x & 63;
    int sub = L >> 4;
    int c16 = L & 15;
    int hd = c16 >> 2;
    int beg = row_start[v], deg = count[v];
    float edv = ed1[v * HEADS + hd];
    const int* ep = esrc + beg;
    float lacc = 0.f;
    float acc[8];
#pragma unroll
    for (int i = 0; i < 8; i++) acc[i] = 0.f;
    const uint4* zq = (const uint4*)z1b;   // row = 16 uint4

    for (int j0 = 0; j0 < deg; j0 += 32) {
        int se[8];
        uint4 u[8];
        float ev[8];
#pragma unroll
        for (int g = 0; g < 8; g++) {
            if (j0 + g * 4 < deg) {               // wave-uniform
                int e = j0 + g * 4 + sub;
                se[g] = ep[(e < deg) ? e : 0];
            }
        }
#pragma unroll
        for (int g = 0; g < 8; g++) {
            if (j0 + g * 4 < deg) {
                u[g] = zq[(size_t)se[g] * 16 + c16];
                ev[g] = es1[se[g] * HEADS + hd];
            }
        }
#pragma unroll
        for (int g = 0; g < 8; g++) {
            if (j0 + g * 4 < deg) {
                bool val = (j0 + g * 4 + sub) < deg;
                float q = val ? __expf(lrelu(ev[g] + edv)) : 0.f;
                lacc += q;
                acc[0] = fmaf(q, bflo(u[g].x), acc[0]);
                acc[1] = fmaf(q, bfhi(u[g].x), acc[1]);
                acc[2] = fmaf(q, bflo(u[g].y), acc[2]);
                acc[3] = fmaf(q, bfhi(u[g].y), acc[3]);
                acc[4] = fmaf(q, bflo(u[g].z), acc[4]);
                acc[5] = fmaf(q, bfhi(u[g].z), acc[5]);
                acc[6] = fmaf(q, bflo(u[g].w), acc[6]);
                acc[7] = fmaf(q, bfhi(u[g].w), acc[7]);
            }
        }
    }
    // l per head: lanes of head hd differ in bits 0,1 (c16&3) and 4,5 (sub);
    // sum over them counts each edge 4x.
    lacc += __shfl_xor(lacc, 1);
    lacc += __shfl_xor(lacc, 2);
    lacc += __shfl_xor(lacc, 16);
    lacc += __shfl_xor(lacc, 32);
    lacc *= 0.25f;
    // combine 4 edge-subgroups (bits 4,5)
#pragma unroll
    for (int i = 0; i < 8; i++) {
        acc[i] += __shfl_xor(acc[i], 16);
        acc[i] += __shfl_xor(acc[i], 32);
    }
    if (L < 16) {
        float inv = (deg > 0) ? 1.f / lacc : 0.f;
        unsigned w[4];
#pragma unroll
        for (int i = 0; i < 4; i++) {
            float r0 = acc[2 * i] * inv;
            float r1 = acc[2 * i + 1] * inv;
            r0 = r0 > 0.f ? r0 : __expf(r0) - 1.f;   // elu
            r1 = r1 > 0.f ? r1 : __expf(r1) - 1.f;
            w[i] = (unsigned)rne_bf16(r0) | ((unsigned)rne_bf16(r1) << 16);
        }
        uint4* dst = (uint4*)(h1b + (size_t)v * 128 + c16 * 8);
        *dst = make_uint4(w[0], w[1], w[2], w[3]);
    }
}

// ---------------- Layer 2 projection via MFMA (bf16 A, no split) ----------------

__global__ void __launch_bounds__(256) proj2_mfma(
        const __hip_bfloat16* __restrict__ h1b, const unsigned short* __restrict__ Bh,
        const unsigned short* __restrict__ Bl, __hip_bfloat16* __restrict__ z2b,
        float* __restrict__ es2, float* __restrict__ ed2) {
    int tid = threadIdx.x;
    int wave = tid >> 6;
    int L = tid & 63;
    int q = L >> 4, L15 = L & 15;
    int n0 = blockIdx.x * 64 + wave * 16;

    int rowA = n0 + L15;
    int rrA = rowA < N_NODES ? rowA : N_NODES - 1;
    const bf16x8* hq = (const bf16x8*)(h1b + (size_t)rrA * 128);

    f32x4 acc[5];
#pragma unroll
    for (int nt = 0; nt < 5; nt++) acc[nt] = (f32x4)(0.f);

#pragma unroll
    for (int s = 0; s < 4; s++) {
        bf16x8 a = hq[s * 4 + q];   // channels s*32 + q*8 .. +7
        const bf16x8* bhp = (const bf16x8*)(Bh + ((size_t)s * 5 * 64) * 8 + (size_t)L * 8);
        const bf16x8* blp = (const bf16x8*)(Bl + ((size_t)s * 5 * 64) * 8 + (size_t)L * 8);
#pragma unroll
        for (int nt = 0; nt < 5; nt++)
            acc[nt] = __builtin_amdgcn_mfma_f32_16x16x32_bf16(a, bhp[nt * 64], acc[nt], 0, 0, 0);
        acc[4] = __builtin_amdgcn_mfma_f32_16x16x32_bf16(a, blp[4 * 64], acc[4], 0, 0, 0);
    }

#pragma unroll
    for (int r = 0; r < 4; r++) {
        int rowc = n0 + q * 4 + r;
        if (rowc < N_NODES) {
#pragma unroll
            for (int nt = 0; nt < 4; nt++)
                z2b[(size_t)rowc * OUT_DIM + nt * 16 + L15] = __float2bfloat16(acc[nt][r]);
            if (L15 == 0) es2[rowc] = acc[4][r];
            else if (L15 == 1) ed2[rowc] = acc[4][r];
        }
    }
}

// ---------------- Layer 2 aggregation (final output) ----------------
// One wave per node; lane L = (sub=L>>3, c8=L&7); inline p (es2[se] is a
// broadcast within each 8-lane subgroup).

__global__ void __launch_bounds__(256) agg2_kernel(
        const __hip_bfloat16* __restrict__ z2b, const float* __restrict__ es2,
        const float* __restrict__ ed2, const int* __restrict__ row_start,
        const int* __restrict__ count, const int* __restrict__ esrc,
        float* __restrict__ out) {
    int v = blockIdx.x * 4 + (threadIdx.x >> 6);
    int L = threadIdx.x & 63;
    int sub = L >> 3;
    int c8 = L & 7;
    int beg = row_start[v], deg = count[v];
    float edv = ed2[v];
    const int* ep = esrc + beg;
    float lacc = 0.f;
    float acc[8];
#pragma unroll
    for (int i = 0; i < 8; i++) acc[i] = 0.f;
    const uint4* zq = (const uint4*)z2b;   // row = 8 uint4

    for (int j0 = 0; j0 < deg; j0 += 32) {
        int se[4];
        uint4 u[4];
        float ev[4];
#pragma unroll
        for (int g = 0; g < 4; g++) {
            if (j0 + g * 8 < deg) {               // wave-uniform
                int e = j0 + g * 8 + sub;
                se[g] = ep[(e < deg) ? e : 0];
            }
        }
#pragma unroll
        for (int g = 0; g < 4; g++) {
            if (j0 + g * 8 < deg) {
                u[g] = zq[(size_t)se[g] * 8 + c8];
                ev[g] = es2[se[g]];
            }
        }
#pragma unroll
        for (int g = 0; g < 4; g++) {
            if (j0 + g * 8 < deg) {
                bool val = (j0 + g * 8 + sub) < deg;
                float q = val ? __expf(lrelu(ev[g] + edv)) : 0.f;
                lacc += q;
                acc[0] = fmaf(q, bflo(u[g].x), acc[0]);
                acc[1] = fmaf(q, bfhi(u[g].x), acc[1]);
                acc[2] = fmaf(q, bflo(u[g].y), acc[2]);
                acc[3] = fmaf(q, bfhi(u[g].y), acc[3]);
                acc[4] = fmaf(q, bflo(u[g].z), acc[4]);
                acc[5] = fmaf(q, bfhi(u[g].z), acc[5]);
                acc[6] = fmaf(q, bflo(u[g].w), acc[6]);
                acc[7] = fmaf(q, bfhi(u[g].w), acc[7]);
            }
        }
    }
    // l: q identical across c8 within a subgroup; sum over subs (bits 3,4,5)
    lacc += __shfl_xor(lacc, 8);
    lacc += __shfl_xor(lacc, 16);
    lacc += __shfl_xor(lacc, 32);
    // combine 8 edge-subgroups
#pragma unroll
    for (int i = 0; i < 8; i++) {
        acc[i] += __shfl_xor(acc[i], 8);
        acc[i] += __shfl_xor(acc[i], 16);
        acc[i] += __shfl_xor(acc[i], 32);
    }
    if (L < 8) {
        float inv = (deg > 0) ? 1.f / lacc : 0.f;
        float4 r0, r1;
#pragma unroll
        for (int i = 0; i < 8; i++) {
            float r = acc[i] * inv;
            if (i < 4) (&r0.x)[i] = r;
            else (&r1.x)[i - 4] = r;
        }
        float* dst = out + (size_t)v * OUT_DIM + c8 * 8;
        *(float4*)dst = r0;
        *(float4*)(dst + 4) = r1;
    }
}

// ---------------- launch ----------------

extern "C" void kernel_launch(void* const* d_in, const int* in_sizes, int n_in,
                              void* d_out, int out_size, void* d_ws, size_t ws_size,
                              hipStream_t stream) {
    const float* h  = (const float*)d_in[0];
    const int* src  = (const int*)d_in[1];
    const int* dst  = (const int*)d_in[2];
    const float* W1 = (const float*)d_in[3];
    const float* a1 = (const float*)d_in[4];
    const float* W2 = (const float*)d_in[5];
    const float* a2 = (const float*)d_in[6];
    float* out = (float*)d_out;

    char* w = (char*)d_ws;
    size_t off = 0;
    auto alloc = [&](size_t bytes) {
        void* p = w + off;
        off = (off + bytes + 255) & ~(size_t)255;
        return p;
    };
    __hip_bfloat16* z1b = (__hip_bfloat16*)alloc((size_t)N_NODES * 128 * 2);
    float* es1 = (float*)alloc((size_t)N_NODES * HEADS * 4);
    float* ed1 = (float*)alloc((size_t)N_NODES * HEADS * 4);
    __hip_bfloat16* h1b = (__hip_bfloat16*)alloc((size_t)N_NODES * 128 * 2);
    __hip_bfloat16* z2b = (__hip_bfloat16*)alloc((size_t)N_NODES * OUT_DIM * 2);
    float* es2 = (float*)alloc((size_t)N_NODES * 4);
    float* ed2 = (float*)alloc((size_t)N_NODES * 4);
    int* count     = (int*)alloc((size_t)N_NODES * 4);
    int* row_start = (int*)alloc((size_t)N_NODES * 4);
    int* rank      = (int*)alloc((size_t)N_EDGES * 4);
    int* blocksum  = (int*)alloc((size_t)SCAN_BLOCKS * 4);
    int* esrc      = (int*)alloc((size_t)N_EDGES * 4);
    unsigned short* Bf1h = (unsigned short*)alloc((size_t)8 * 9 * 64 * 8 * 2);
    unsigned short* Bf1l = (unsigned short*)alloc((size_t)8 * 9 * 64 * 8 * 2);
    unsigned short* Bf2h = (unsigned short*)alloc((size_t)4 * 5 * 64 * 8 * 2);
    unsigned short* Bf2l = (unsigned short*)alloc((size_t)4 * 5 * 64 * 8 * 2);

    prep_kernel<<<256, 256, 0, stream>>>(W1, a1, W2, a2, Bf1h, Bf1l, Bf2h, Bf2l, count);
    hist_kernel<<<(N_EDGES + 255) / 256, 256, 0, stream>>>(dst, count, rank);
    scan1_kernel<<<SCAN_BLOCKS, 256, 0, stream>>>(count, row_start, blocksum);
    scan23_kernel<<<SCAN_BLOCKS, 256, 0, stream>>>(row_start, blocksum);
    scatter_kernel<<<(N_EDGES + 255) / 256, 256, 0, stream>>>(src, dst, rank, row_start, esrc);

    const int MBLK = (N_NODES + 63) / 64;  // 782
    proj1_mfma<<<MBLK, 256, 0, stream>>>(h, Bf1h, Bf1l, z1b, es1, ed1);
    agg1_kernel<<<N_NODES / 4, 256, 0, stream>>>(z1b, es1, ed1, row_start, count, esrc, h1b);
    proj2_mfma<<<MBLK, 256, 0, stream>>>(h1b, Bf2h, Bf2l, z2b, es2, ed2);
    agg2_kernel<<<N_NODES / 4, 256, 0, stream>>>(z2b, es2, ed2, row_start, count, esrc, out);
}